// Round 4
// baseline (217.516 us; speedup 1.0000x reference)
//
#include <hip/hip_runtime.h>
#include <math.h>
#include <stdint.h>

#define S_LEN 1024
#define D_DIM 64
#define BH    32
#define KSHIFT 13
#define NBINS 130048u             // 0x3F800000 >> 13 : |score| < 1.0, 18-bit keys
#define PV_LO  119808u            // pv LDS table: |s| >= 2^-10 (0x3A800000>>13)
#define NPVT   10240u             // pv table bins (NBINS - PV_LO)
#define HIST_LO 117760u           // hist LDS range: |s| >= 2^-12
#define NHOT_H  12288u            // NBINS - HIST_LO
#define NCHUNK 254                // NBINS / 512
#define HBLK   256                // hist kernel blocks (1024 thr each)
#define INV_NM1 (1.0f/33554431.0f)
#define INV_N   (2.9802322387695312e-08f)  // 1/2^25
#define FIX_TH  1e-4f             // |s| below this -> wave-coop fp64 recompute (~21K elems)

// score layout is J-TILE-MAJOR: flat = ((bh*16 + jt)*1024 + i)*64 + jin
// where j = jt*64 + jin. Makes pv's 16-row MFMA fragment gather a dense 4KB
// single-page access (was 16 x 128B granules scattered across 64KB at 4KB
// stride -> 1.67 TB/s HBM ceiling, occupancy-independent, r0==r3 duration).
// Vt tiled the same way: Vt[((bh*16 + jt)*64 + d)*64 + jin].

typedef _Float16 half8 __attribute__((ext_vector_type(8)));
typedef short    short8 __attribute__((ext_vector_type(8)));
typedef float    floatx4 __attribute__((ext_vector_type(4)));

// ---------------- row norms: 1/(||row||+1e-5), fp64 + fp32 copies ----------------
__global__ __launch_bounds__(256) void norms_kernel(
    const float* __restrict__ Q, const float* __restrict__ K,
    double* __restrict__ qinvD, double* __restrict__ kinvD,
    float* __restrict__ qinvF, float* __restrict__ kinvF) {
  int row  = blockIdx.x * 4 + (threadIdx.x >> 6);
  int lane = threadIdx.x & 63;
  const float* src; double* dstD; float* dstF; int r = row;
  if (row < BH * S_LEN) { src = Q; dstD = qinvD; dstF = qinvF; }
  else                  { src = K; dstD = kinvD; dstF = kinvF; r = row - BH * S_LEN; }
  double v = (double)src[(size_t)r * D_DIM + lane];
  double s = v * v;
  #pragma unroll
  for (int off = 32; off; off >>= 1) s += __shfl_down(s, off);
  if (lane == 0) {
    double inv = 1.0 / (sqrt(s) + 1e-5);
    dstD[r] = inv;
    dstF[r] = (float)inv;
  }
}

// bf16 split helper: x -> hi (RNE) + lo (RZ of residual), as raw bf16 bit patterns
__device__ __forceinline__ void bf16_split(float x, short& hi, short& lo) {
  unsigned u = __float_as_uint(x);
  unsigned h = (u + 0x7FFFu + ((u >> 16) & 1u)) >> 16;   // RNE to bf16
  float hf = __uint_as_float(h << 16);
  float lf = x - hf;                                     // exact (Sterbenz)
  hi = (short)h;
  lo = (short)(__float_as_uint(lf) >> 16);               // RZ to bf16
}

// ---------------- QK^T via bf16-split MFMA (hi*hi + hi*lo + lo*hi) ----------------
__global__ __launch_bounds__(256) void qk_mfma_kernel(
    const float* __restrict__ Q, const float* __restrict__ K,
    const float* __restrict__ qinvF, const float* __restrict__ kinvF,
    float* __restrict__ score) {
  __shared__ short Qhi[64][72], Qlo[64][72];   // stride 72 shorts = 144 B: 16B-aligned, 2-way banks
  __shared__ short Khi[64][72], Klo[64][72];
  int bh = blockIdx.z;
  int i0 = blockIdx.y * 64;
  int j0 = blockIdx.x * 64;
  int tid = threadIdx.x;
  const float* Qb = Q + ((size_t)bh * S_LEN + i0) * D_DIM;
  const float* Kb = K + ((size_t)bh * S_LEN + j0) * D_DIM;
  #pragma unroll
  for (int l = 0; l < 4; ++l) {
    int idx4 = l * 256 + tid;          // 0..1023 float4 of 64x64 tile
    int row  = idx4 >> 4;
    int c4   = idx4 & 15;
    float qi = qinvF[(size_t)bh * S_LEN + i0 + row];
    float4 v = ((const float4*)Qb)[idx4];
    float qv[4] = {v.x * qi, v.y * qi, v.z * qi, v.w * qi};
    short qh[4], ql[4];
    #pragma unroll
    for (int c = 0; c < 4; ++c) bf16_split(qv[c], qh[c], ql[c]);
    *(short4*)&Qhi[row][c4 * 4] = make_short4(qh[0], qh[1], qh[2], qh[3]);
    *(short4*)&Qlo[row][c4 * 4] = make_short4(ql[0], ql[1], ql[2], ql[3]);
    float kj = kinvF[(size_t)bh * S_LEN + j0 + row];
    float4 w = ((const float4*)Kb)[idx4];
    float kv[4] = {w.x * kj, w.y * kj, w.z * kj, w.w * kj};
    short kh[4], kl[4];
    #pragma unroll
    for (int c = 0; c < 4; ++c) bf16_split(kv[c], kh[c], kl[c]);
    *(short4*)&Khi[row][c4 * 4] = make_short4(kh[0], kh[1], kh[2], kh[3]);
    *(short4*)&Klo[row][c4 * 4] = make_short4(kl[0], kl[1], kl[2], kl[3]);
  }
  __syncthreads();
  int wave = tid >> 6;
  int lane = tid & 63;
  int m    = lane & 15;
  int quad = lane >> 4;
  floatx4 acc[4];
  #pragma unroll
  for (int n = 0; n < 4; ++n) acc[n] = (floatx4){0.f, 0.f, 0.f, 0.f};
  #pragma unroll
  for (int ks = 0; ks < 2; ++ks) {
    int kb = ks * 32 + quad * 8;
    short8 a_hi = *(const short8*)&Qhi[wave * 16 + m][kb];
    short8 a_lo = *(const short8*)&Qlo[wave * 16 + m][kb];
    #pragma unroll
    for (int nt = 0; nt < 4; ++nt) {
      short8 b_hi = *(const short8*)&Khi[nt * 16 + m][kb];
      short8 b_lo = *(const short8*)&Klo[nt * 16 + m][kb];
      acc[nt] = __builtin_amdgcn_mfma_f32_16x16x32_bf16(a_hi, b_hi, acc[nt], 0, 0, 0);
      acc[nt] = __builtin_amdgcn_mfma_f32_16x16x32_bf16(a_hi, b_lo, acc[nt], 0, 0, 0);
      acc[nt] = __builtin_amdgcn_mfma_f32_16x16x32_bf16(a_lo, b_hi, acc[nt], 0, 0, 0);
    }
  }
  // C/D: row = quad*4 + r, col = lane&15.  Tile-major store:
  // flat = bh*2^20 + jt*65536 + i*64 + jin,  jt = j0>>6, jin = nt*16 + m.
  #pragma unroll
  for (int r = 0; r < 4; ++r) {
    float* op = score + (size_t)bh * 1048576 + (size_t)(j0 >> 6) * 65536
              + (size_t)(i0 + wave * 16 + quad * 4 + r) * 64 + m;
    #pragma unroll
    for (int nt = 0; nt < 4; ++nt)
      op[nt * 16] = acc[nt][r];
  }
}

// ------- histogram (LDS hot range, 1024thr/2 blocks-per-CU) + fused fp64 fixup -------
__global__ __launch_bounds__(1024) void hist_kernel(
    float* __restrict__ score, const float* __restrict__ Q, const float* __restrict__ K,
    const double* __restrict__ qinvD, const double* __restrict__ kinvD,
    unsigned* __restrict__ hist, unsigned char* __restrict__ partial) {
  __shared__ unsigned lh[NHOT_H];
  int tid = threadIdx.x;
  int lane = tid & 63;
  for (unsigned i = tid; i < NHOT_H; i += 1024) lh[i] = 0u;
  __syncthreads();
  // 8,388,608 float4 total; 32768 per block; 32 iters of 1024 threads
  const float4* p = (const float4*)score + (size_t)blockIdx.x * 32768;
  #pragma unroll 2
  for (int it = 0; it < 32; ++it) {
    float4 v = p[it * 1024 + tid];
    float vv[4] = {v.x, v.y, v.z, v.w};
    // ---- rare fp64 fixup (wave-cooperative, no global atomics) ----
    bool anyf = (fabsf(vv[0]) < FIX_TH) | (fabsf(vv[1]) < FIX_TH) |
                (fabsf(vv[2]) < FIX_TH) | (fabsf(vv[3]) < FIX_TH);
    unsigned long long am = __ballot(anyf);
    while (am) {
      int src = (int)(__ffsll((long long)am) - 1);
      am &= am - 1;
      unsigned base4 = (unsigned)(blockIdx.x * 32768u + (unsigned)(it * 1024 + tid));
      unsigned b4 = __shfl(base4, src);
      #pragma unroll
      for (int c = 0; c < 4; ++c) {
        float sc = __shfl(vv[c], src);
        if (fabsf(sc) < FIX_TH) {
          unsigned flat = b4 * 4u + (unsigned)c;
          // tile-major decode: flat = ((bh*16 + jt)*1024 + i)*64 + jin
          unsigned bh = flat >> 20;
          unsigned rem = flat & 0xFFFFFu;
          unsigned jt = rem >> 16;
          unsigned i  = (rem >> 6) & 1023u;
          unsigned j  = jt * 64u + (rem & 63u);
          double qd = (double)Q[((size_t)bh * S_LEN + i) * D_DIM + lane];
          double kd = (double)K[((size_t)bh * S_LEN + j) * D_DIM + lane];
          double pd = qd * kd;
          #pragma unroll
          for (int off = 32; off; off >>= 1) pd += __shfl_down(pd, off);
          float corr = 0.f;
          if (lane == 0)
            corr = (float)(pd * qinvD[(size_t)bh * S_LEN + i] * kinvD[(size_t)bh * S_LEN + j]);
          corr = __shfl(corr, 0);
          if (lane == src) {
            vv[c] = corr;
            score[(size_t)flat] = corr;
          }
        }
      }
    }
    // ---- binning ----
    #pragma unroll
    for (int c = 0; c < 4; ++c) {
      unsigned b = __float_as_uint(fabsf(vv[c])) >> KSHIFT;
      if (b >= NBINS) b = NBINS - 1u;
      if (b >= HIST_LO) atomicAdd(&lh[b - HIST_LO], 1u);
      else              atomicAdd(&hist[b], 1u);     // rare (~1.6e-3 of values)
    }
  }
  __syncthreads();
  unsigned char* dst = partial + (size_t)blockIdx.x * NHOT_H;
  for (unsigned i = tid; i < NHOT_H; i += 1024) dst[i] = (unsigned char)lh[i];
}

// ---------------- reduce u8 partial histograms into hist hot range ----------------
__global__ __launch_bounds__(256) void hreduce_kernel(
    const unsigned char* __restrict__ partial, unsigned* __restrict__ hist) {
  unsigned bin = blockIdx.x * 256 + threadIdx.x;   // 48 blocks * 256 = 12288
  unsigned s = 0;
  #pragma unroll 8
  for (int b = 0; b < HBLK; ++b) s += (unsigned)partial[(size_t)b * NHOT_H + bin];
  hist[HIST_LO + bin] = s;
}

// ---------------- V (fp32 [j][d]) -> Vt tiled fp16 [jt][d][jin] ----------------
__global__ __launch_bounds__(256) void vt_kernel(
    const float* __restrict__ V, _Float16* __restrict__ Vt) {
  __shared__ _Float16 T[64][72];
  int bh = blockIdx.y, j0 = blockIdx.x * 64, tid = threadIdx.x;
  const float* Vb = V + ((size_t)bh * S_LEN + j0) * D_DIM;
  #pragma unroll
  for (int l = 0; l < 4; ++l) {
    int idx = l * 256 + tid;
    int jr = idx >> 4, d4 = idx & 15;
    float4 v = ((const float4*)Vb)[idx];
    T[d4*4+0][jr] = (_Float16)v.x;
    T[d4*4+1][jr] = (_Float16)v.y;
    T[d4*4+2][jr] = (_Float16)v.z;
    T[d4*4+3][jr] = (_Float16)v.w;
  }
  __syncthreads();
  // tile (bh, jt=blockIdx.x): Vt[((bh*16+jt)*64 + d)*64 + jin]
  _Float16* Ob = Vt + (size_t)(bh * 16 + blockIdx.x) * 4096;
  #pragma unroll
  for (int l = 0; l < 2; ++l) {
    int idx = l * 256 + tid;
    int d = idx >> 3, jc = idx & 7;
    uint4 val = *(const uint4*)&T[d][jc*8];
    *(uint4*)(Ob + (size_t)d * 64 + jc*8) = val;
  }
}

// ---------------- histogram exclusive scan (3 stages), chunk=512 ----------------
__global__ __launch_bounds__(256) void scan1_kernel(const unsigned* __restrict__ hist,
                                                    unsigned* __restrict__ csum) {
  __shared__ unsigned sd[256];
  int c = blockIdx.x, t = threadIdx.x;
  const unsigned* p = hist + (size_t)c * 512;
  sd[t] = p[t] + p[t + 256];
  __syncthreads();
  for (int off = 128; off; off >>= 1) {
    if (t < off) sd[t] += sd[t + off];
    __syncthreads();
  }
  if (t == 0) csum[c] = sd[0];
}

__global__ __launch_bounds__(256) void scan2_kernel(unsigned* __restrict__ csum) {
  __shared__ unsigned d[256];
  int t = threadIdx.x;
  unsigned v = (t < NCHUNK) ? csum[t] : 0u;
  d[t] = v; __syncthreads();
  for (int off = 1; off < 256; off <<= 1) {
    unsigned x = (t >= off) ? d[t - off] : 0u;
    __syncthreads();
    d[t] += x;
    __syncthreads();
  }
  if (t < NCHUNK) csum[t] = d[t] - v;   // exclusive
}

// scan3: per-bin midrank -> tTab16[b] = fp16(-log(prob(midrank)))
__global__ __launch_bounds__(256) void scan3_kernel(const unsigned* __restrict__ hist,
                                                    const unsigned* __restrict__ csum,
                                                    _Float16* __restrict__ tTab16) {
  __shared__ unsigned ts[256];
  int c = blockIdx.x, t = threadIdx.x;
  const unsigned* p = hist + (size_t)c * 512 + t * 2;
  unsigned l0 = p[0], l1 = p[1];
  unsigned s = l0 + l1;
  ts[t] = s; __syncthreads();
  for (int off = 1; off < 256; off <<= 1) {
    unsigned x = (t >= off) ? ts[t - off] : 0u;
    __syncthreads();
    ts[t] += x;
    __syncthreads();
  }
  unsigned base = csum[c] + ts[t] - s;
  int idx = c * 512 + t * 2;
  float r0 = (float)base + 0.5f * ((float)l0 - 1.0f);
  tTab16[idx]     = (_Float16)(-__logf(fmaf(r0, INV_NM1, INV_N)));
  float r1 = (float)(base + l0) + 0.5f * ((float)l1 - 1.0f);
  tTab16[idx + 1] = (_Float16)(-__logf(fmaf(r1, INV_NM1, INV_N)));
}

// ---------------- fused map + MFMA P.V + rowsum-normalized epilogue ----------------
// Structure = round-3 (verified): 16 rows/block, 4 waves k-split, dedicated red
// exchange, 37888 B LDS -> 4 blocks/CU. NEW: tile-major score/Vt addressing --
// each wave's fragment load pair now covers one dense 4KB page (score) / 2KB
// window (Vt) instead of 16 x 128B granules at 4KB stride.
__global__ __launch_bounds__(256) void pv_mfma_kernel(
    const float* __restrict__ score, const _Float16* __restrict__ Vt,
    const unsigned short* __restrict__ tTab16, float* __restrict__ out) {
  __shared__ unsigned short ldsT[NPVT];   // 20480 B hot table
  __shared__ float red[4352];             // 17408 B exchange (separate object)
  int tid = threadIdx.x;
  {
    const unsigned* gsrc = (const unsigned*)(tTab16 + PV_LO);
    unsigned* ldst = (unsigned*)ldsT;
    #pragma unroll
    for (int i = 0; i < 20; ++i)          // 20*256 uints = 10240 ushorts
      ldst[i * 256 + tid] = gsrc[i * 256 + tid];
  }
  __syncthreads();

  int bh   = blockIdx.y;
  int wave = tid >> 6;
  int lane = tid & 63;
  int m    = lane & 15;
  int quad = lane >> 4;
  int i0   = blockIdx.x * 16;
  // tile-major: score + bh*2^20 + jt*65536 + (i0+m)*64 + jin
  const float*    Sb = score + (size_t)bh * 1048576 + (size_t)(i0 + m) * 64;
  const _Float16* Vb = Vt + (size_t)bh * 65536;
  floatx4 acc[4];
  #pragma unroll
  for (int n = 0; n < 4; ++n) acc[n] = (floatx4){0.f, 0.f, 0.f, 0.f};
  float rsum = 0.f;

  // wave w covers k in [w*256, (w+1)*256): 8 iterations of 32 cols
  for (int ks = 0; ks < 8; ++ks) {
    int k0  = wave * 256 + ks * 32 + quad * 8;
    int jt  = k0 >> 6;
    int jin = k0 & 63;
    const float* sp = Sb + (size_t)jt * 65536 + jin;
    float4 s0 = *(const float4*)(sp);
    float4 s1 = *(const float4*)(sp + 4);
    float sv[8] = {s0.x, s0.y, s0.z, s0.w, s1.x, s1.y, s1.z, s1.w};
    union { unsigned short u[8]; half8 h; } af;
    #pragma unroll
    for (int e = 0; e < 8; ++e) {
      unsigned u = __float_as_uint(sv[e]);
      unsigned a = u & 0x7fffffffu;
      unsigned b = a >> KSHIFT;
      if (b > NBINS - 1u) b = NBINS - 1u;
      unsigned short tb;
      if (b >= PV_LO) tb = ldsT[b - PV_LO];
      else            tb = tTab16[b];      // ~0.6% of lookups, L2-resident table
      if (a == 0u) tb = 0;
      af.u[e] = (unsigned short)(tb ^ ((u >> 16) & 0x8000u));
      unsigned short tabs = (unsigned short)(tb & 0x7fffu);
      _Float16 th = __builtin_bit_cast(_Float16, tabs);
      rsum += (float)th;
    }
    half8 bf[4];
    #pragma unroll
    for (int n = 0; n < 4; ++n)
      bf[n] = *(const half8*)(Vb + (size_t)jt * 4096 + (size_t)(n * 16 + m) * 64 + jin);
    #pragma unroll
    for (int n = 0; n < 4; ++n)
      acc[n] = __builtin_amdgcn_mfma_f32_16x16x32_f16(af.h, bf[n], acc[n], 0, 0, 0);
  }

  // ---- cross-wave exchange into dedicated red buffer ----
  // C/D fragment: row = quad*4 + r, col = n*16 + m (verified mapping).
  #pragma unroll
  for (int n = 0; n < 4; ++n)
    #pragma unroll
    for (int r = 0; r < 4; ++r)
      red[(wave * 16 + quad * 4 + r) * 64 + n * 16 + m] = acc[n][r];
  red[4096 + wave * 64 + lane] = rsum;   // raw per-lane rsum (row = lane&15)
  __syncthreads();

  // ---- cooperative reduce + normalize + store: 16 rows x 64 cols ----
  int col = tid & 63;
  int rq  = tid >> 6;
  #pragma unroll
  for (int t = 0; t < 4; ++t) {
    int row = rq * 4 + t;
    float s = 0.f;
    #pragma unroll
    for (int w = 0; w < 4; ++w) s += red[(w * 16 + row) * 64 + col];
    float rs = 0.f;
    #pragma unroll
    for (int w = 0; w < 4; ++w)
      #pragma unroll
      for (int q = 0; q < 4; ++q)
        rs += red[4096 + w * 64 + q * 16 + row];
    out[((size_t)bh * S_LEN + i0 + row) * D_DIM + col] = s / rs;
  }
}

// ---------------- launch ----------------
extern "C" void kernel_launch(void* const* d_in, const int* in_sizes, int n_in,
                              void* d_out, int out_size, void* d_ws, size_t ws_size,
                              hipStream_t stream) {
  const float* Q = (const float*)d_in[0];
  const float* K = (const float*)d_in[1];
  const float* V = (const float*)d_in[2];
  float* out = (float*)d_out;
  char* ws = (char*)d_ws;
  // Layout (max byte used < round-7-proven 142,077,952):
  //   score [0, 134217728) ; hist [134217728, 134737920)
  //   P = 134737920:
  //     partial u8 P+0 .. P+3145728            (256*12288, live hist->hreduce)
  //     qinvD P+3145728, kinvD P+3407872       (256 KB each, live norms->hist)
  //     qinvF P+3670016, kinvF P+3801088       (128 KB each, live norms->qk)
  //     Vt    P+0 .. P+4194304                 (live vt->pv; aliases partial/qinv*/kinv*, all dead)
  //     csum  P+4456448 (1016 B, scan1->scan3)
  //     tTab16 P+4457472 (260096 B, scan3->pv)
  float*         score   = (float*)(ws);
  unsigned*      hist    = (unsigned*)(ws + 134217728);
  unsigned char* partial = (unsigned char*)(ws + 134737920);
  double*        qinvD   = (double*)(ws + 137883648);
  double*        kinvD   = (double*)(ws + 138145792);
  float*         qinvF   = (float*)(ws + 138407936);
  float*         kinvF   = (float*)(ws + 138539008);
  _Float16*      Vt      = (_Float16*)(ws + 134737920);
  unsigned*      csum    = (unsigned*)(ws + 139194368);
  _Float16*      tTab16  = (_Float16*)(ws + 139195392);

  hipMemsetAsync(hist, 0, NBINS * sizeof(unsigned), stream);
  norms_kernel<<<(2 * BH * S_LEN) / 4, 256, 0, stream>>>(Q, K, qinvD, kinvD, qinvF, kinvF);
  qk_mfma_kernel<<<dim3(16, 16, BH), 256, 0, stream>>>(Q, K, qinvF, kinvF, score);
  hist_kernel<<<HBLK, 1024, 0, stream>>>(score, Q, K, qinvD, kinvD, hist, partial);
  hreduce_kernel<<<NHOT_H / 256, 256, 0, stream>>>(partial, hist);
  vt_kernel<<<dim3(16, BH), 256, 0, stream>>>(V, Vt);
  scan1_kernel<<<NCHUNK, 256, 0, stream>>>(hist, csum);
  scan2_kernel<<<1, 256, 0, stream>>>(csum);
  scan3_kernel<<<NCHUNK, 256, 0, stream>>>(hist, csum, tTab16);
  pv_mfma_kernel<<<dim3(S_LEN / 16, BH), 256, 0, stream>>>(
      score, Vt, (const unsigned short*)tTab16, out);
}

// Round 5
// 201.040 us; speedup vs baseline: 1.0820x; 1.0820x over previous
//
#include <hip/hip_runtime.h>
#include <math.h>
#include <stdint.h>

#define S_LEN 1024
#define D_DIM 64
#define BH    32
#define KSHIFT 13
#define NBINS 130048u             // 0x3F800000 >> 13 : |score| < 1.0, 18-bit fp32 bins
#define CODE_BASE 97280u          // bins below this (|s| < 2^-32, ~0 elems) clamp to code 0
#define NB2   32768u              // 15-bit code bins = NBINS - CODE_BASE
#define HIST_LO_C 20480u          // hist LDS window: codes for |s| >= 2^-12
#define NHOT_H  12288u            // NB2 - HIST_LO_C
#define PV_LO_C 22528u            // pv LDS table: codes for |s| >= 2^-10
#define NPVT   10240u             // NB2 - PV_LO_C
#define NCHUNK 64                 // NB2 / 512
#define HBLK   256                // hist kernel blocks (1024 thr each)
#define INV_NM1 (1.0f/33554431.0f)
#define INV_N   (2.9802322387695312e-08f)  // 1/2^25
#define FIX_TH  1e-4f             // |s| below this -> wave-coop fp64 recompute in qk (~21K elems)

// Score is stored ONLY as a u16 code: sign(bit15) | (fp32-bin - CODE_BASE).
// Rationale (r0/r3/r4 counters): pv was pinned at 55 us / 1.68 TB/s with
// hbm_bytes ~92 MB invariant across occupancy x1.85, dense layout, 2x L2
// traffic -> the L2-miss path (latency x concurrency) is the cap; only
// reducing miss BYTES helps. Codes halve score bytes at qk-write, hist-read,
// pv-read; the bin/scan/table pipeline is bit-identical (same integer bins).
// Code layout is J-TILE-MAJOR: flat = ((bh*16 + jt)*1024 + i)*64 + jin.

typedef _Float16 half8 __attribute__((ext_vector_type(8)));
typedef short    short8 __attribute__((ext_vector_type(8)));
typedef float    floatx4 __attribute__((ext_vector_type(4)));

// ---------------- row norms: 1/(||row||+1e-5), fp64 + fp32 copies ----------------
__global__ __launch_bounds__(256) void norms_kernel(
    const float* __restrict__ Q, const float* __restrict__ K,
    double* __restrict__ qinvD, double* __restrict__ kinvD,
    float* __restrict__ qinvF, float* __restrict__ kinvF) {
  int row  = blockIdx.x * 4 + (threadIdx.x >> 6);
  int lane = threadIdx.x & 63;
  const float* src; double* dstD; float* dstF; int r = row;
  if (row < BH * S_LEN) { src = Q; dstD = qinvD; dstF = qinvF; }
  else                  { src = K; dstD = kinvD; dstF = kinvF; r = row - BH * S_LEN; }
  double v = (double)src[(size_t)r * D_DIM + lane];
  double s = v * v;
  #pragma unroll
  for (int off = 32; off; off >>= 1) s += __shfl_down(s, off);
  if (lane == 0) {
    double inv = 1.0 / (sqrt(s) + 1e-5);
    dstD[r] = inv;
    dstF[r] = (float)inv;
  }
}

// bf16 split helper: x -> hi (RNE) + lo (RZ of residual), as raw bf16 bit patterns
__device__ __forceinline__ void bf16_split(float x, short& hi, short& lo) {
  unsigned u = __float_as_uint(x);
  unsigned h = (u + 0x7FFFu + ((u >> 16) & 1u)) >> 16;   // RNE to bf16
  float hf = __uint_as_float(h << 16);
  float lf = x - hf;                                     // exact (Sterbenz)
  hi = (short)h;
  lo = (short)(__float_as_uint(lf) >> 16);               // RZ to bf16
}

// -------- QK^T via bf16-split MFMA + fused fp64 fixup + bin -> u16 code --------
__global__ __launch_bounds__(256) void qk_mfma_kernel(
    const float* __restrict__ Q, const float* __restrict__ K,
    const float* __restrict__ qinvF, const float* __restrict__ kinvF,
    const double* __restrict__ qinvD, const double* __restrict__ kinvD,
    unsigned short* __restrict__ code16) {
  __shared__ short Qhi[64][72], Qlo[64][72];   // stride 72 shorts = 144 B: 16B-aligned, 2-way banks
  __shared__ short Khi[64][72], Klo[64][72];
  int bh = blockIdx.z;
  int i0 = blockIdx.y * 64;
  int j0 = blockIdx.x * 64;
  int tid = threadIdx.x;
  const float* Qb = Q + ((size_t)bh * S_LEN + i0) * D_DIM;
  const float* Kb = K + ((size_t)bh * S_LEN + j0) * D_DIM;
  #pragma unroll
  for (int l = 0; l < 4; ++l) {
    int idx4 = l * 256 + tid;          // 0..1023 float4 of 64x64 tile
    int row  = idx4 >> 4;
    int c4   = idx4 & 15;
    float qi = qinvF[(size_t)bh * S_LEN + i0 + row];
    float4 v = ((const float4*)Qb)[idx4];
    float qv[4] = {v.x * qi, v.y * qi, v.z * qi, v.w * qi};
    short qh[4], ql[4];
    #pragma unroll
    for (int c = 0; c < 4; ++c) bf16_split(qv[c], qh[c], ql[c]);
    *(short4*)&Qhi[row][c4 * 4] = make_short4(qh[0], qh[1], qh[2], qh[3]);
    *(short4*)&Qlo[row][c4 * 4] = make_short4(ql[0], ql[1], ql[2], ql[3]);
    float kj = kinvF[(size_t)bh * S_LEN + j0 + row];
    float4 w = ((const float4*)Kb)[idx4];
    float kv[4] = {w.x * kj, w.y * kj, w.z * kj, w.w * kj};
    short kh[4], kl[4];
    #pragma unroll
    for (int c = 0; c < 4; ++c) bf16_split(kv[c], kh[c], kl[c]);
    *(short4*)&Khi[row][c4 * 4] = make_short4(kh[0], kh[1], kh[2], kh[3]);
    *(short4*)&Klo[row][c4 * 4] = make_short4(kl[0], kl[1], kl[2], kl[3]);
  }
  __syncthreads();
  int wave = tid >> 6;
  int lane = tid & 63;
  int m    = lane & 15;
  int quad = lane >> 4;
  floatx4 acc[4];
  #pragma unroll
  for (int n = 0; n < 4; ++n) acc[n] = (floatx4){0.f, 0.f, 0.f, 0.f};
  #pragma unroll
  for (int ks = 0; ks < 2; ++ks) {
    int kb = ks * 32 + quad * 8;
    short8 a_hi = *(const short8*)&Qhi[wave * 16 + m][kb];
    short8 a_lo = *(const short8*)&Qlo[wave * 16 + m][kb];
    #pragma unroll
    for (int nt = 0; nt < 4; ++nt) {
      short8 b_hi = *(const short8*)&Khi[nt * 16 + m][kb];
      short8 b_lo = *(const short8*)&Klo[nt * 16 + m][kb];
      acc[nt] = __builtin_amdgcn_mfma_f32_16x16x32_bf16(a_hi, b_hi, acc[nt], 0, 0, 0);
      acc[nt] = __builtin_amdgcn_mfma_f32_16x16x32_bf16(a_hi, b_lo, acc[nt], 0, 0, 0);
      acc[nt] = __builtin_amdgcn_mfma_f32_16x16x32_bf16(a_lo, b_hi, acc[nt], 0, 0, 0);
    }
  }
  // ---- rare fp64 fixup (wave-cooperative), moved here from old hist ----
  // lane (quad,m) slot (nt,r): i = i0+wave*16+quad*4+r, j = j0+nt*16+m
  #pragma unroll
  for (int nt = 0; nt < 4; ++nt) {
    #pragma unroll
    for (int r = 0; r < 4; ++r) {
      unsigned long long am = __ballot(fabsf(acc[nt][r]) < FIX_TH);
      while (am) {
        int src = (int)(__ffsll((long long)am) - 1);
        am &= am - 1;
        int i_s = i0 + wave * 16 + (src >> 4) * 4 + r;
        int j_s = j0 + nt * 16 + (src & 15);
        double qd = (double)Q[((size_t)bh * S_LEN + i_s) * D_DIM + lane];
        double kd = (double)K[((size_t)bh * S_LEN + j_s) * D_DIM + lane];
        double pd = qd * kd;
        #pragma unroll
        for (int off = 32; off; off >>= 1) pd += __shfl_down(pd, off);
        float corr = 0.f;
        if (lane == 0)
          corr = (float)(pd * qinvD[(size_t)bh * S_LEN + i_s] * kinvD[(size_t)bh * S_LEN + j_s]);
        corr = __shfl(corr, 0);
        if (lane == src) acc[nt][r] = corr;
      }
    }
  }
  // ---- bin + store u16 codes, tile-major ----
  // C/D: row = quad*4 + r, col = lane&15; flat = bh*2^20 + jt*65536 + i*64 + jin
  #pragma unroll
  for (int r = 0; r < 4; ++r) {
    unsigned short* op = code16 + (size_t)bh * 1048576 + (size_t)(j0 >> 6) * 65536
                       + (size_t)(i0 + wave * 16 + quad * 4 + r) * 64 + m;
    #pragma unroll
    for (int nt = 0; nt < 4; ++nt) {
      unsigned u = __float_as_uint(acc[nt][r]);
      unsigned a = u & 0x7fffffffu;
      unsigned b = a >> KSHIFT;
      if (b > NBINS - 1u) b = NBINS - 1u;
      unsigned c = (b < CODE_BASE) ? 0u : (b - CODE_BASE);
      op[nt * 16] = (unsigned short)(c | ((u >> 16) & 0x8000u));
    }
  }
}

// ---------------- histogram: pure code streamer (LDS hot window) ----------------
__global__ __launch_bounds__(1024) void hist_kernel(
    const uint4* __restrict__ codes, unsigned* __restrict__ hist,
    unsigned char* __restrict__ partial) {
  __shared__ unsigned lh[NHOT_H];
  int tid = threadIdx.x;
  for (unsigned i = tid; i < NHOT_H; i += 1024) lh[i] = 0u;
  __syncthreads();
  // 2^25 u16 codes = 4,194,304 uint4; 16384 per block; 16 iters of 1024 threads
  const uint4* p = codes + (size_t)blockIdx.x * 16384;
  #pragma unroll 2
  for (int it = 0; it < 16; ++it) {
    uint4 w = p[it * 1024 + tid];
    unsigned ws[4] = {w.x, w.y, w.z, w.w};
    #pragma unroll
    for (int k = 0; k < 4; ++k) {
      unsigned c0 = ws[k] & 0x7fffu;
      unsigned c1 = (ws[k] >> 16) & 0x7fffu;
      if (c0 >= HIST_LO_C) atomicAdd(&lh[c0 - HIST_LO_C], 1u);
      else                 atomicAdd(&hist[c0], 1u);    // rare (~1.6e-3)
      if (c1 >= HIST_LO_C) atomicAdd(&lh[c1 - HIST_LO_C], 1u);
      else                 atomicAdd(&hist[c1], 1u);
    }
  }
  __syncthreads();
  unsigned char* dst = partial + (size_t)blockIdx.x * NHOT_H;
  for (unsigned i = tid; i < NHOT_H; i += 1024) dst[i] = (unsigned char)lh[i];
}

// ---------------- reduce u8 partial histograms into hist hot range ----------------
__global__ __launch_bounds__(256) void hreduce_kernel(
    const unsigned char* __restrict__ partial, unsigned* __restrict__ hist) {
  unsigned bin = blockIdx.x * 256 + threadIdx.x;   // 48 blocks * 256 = 12288
  unsigned s = 0;
  #pragma unroll 8
  for (int b = 0; b < HBLK; ++b) s += (unsigned)partial[(size_t)b * NHOT_H + bin];
  hist[HIST_LO_C + bin] = s;
}

// ---------------- V (fp32 [j][d]) -> Vt tiled fp16 [jt][d][jin] ----------------
__global__ __launch_bounds__(256) void vt_kernel(
    const float* __restrict__ V, _Float16* __restrict__ Vt) {
  __shared__ _Float16 T[64][72];
  int bh = blockIdx.y, j0 = blockIdx.x * 64, tid = threadIdx.x;
  const float* Vb = V + ((size_t)bh * S_LEN + j0) * D_DIM;
  #pragma unroll
  for (int l = 0; l < 4; ++l) {
    int idx = l * 256 + tid;
    int jr = idx >> 4, d4 = idx & 15;
    float4 v = ((const float4*)Vb)[idx];
    T[d4*4+0][jr] = (_Float16)v.x;
    T[d4*4+1][jr] = (_Float16)v.y;
    T[d4*4+2][jr] = (_Float16)v.z;
    T[d4*4+3][jr] = (_Float16)v.w;
  }
  __syncthreads();
  _Float16* Ob = Vt + (size_t)(bh * 16 + blockIdx.x) * 4096;
  #pragma unroll
  for (int l = 0; l < 2; ++l) {
    int idx = l * 256 + tid;
    int d = idx >> 3, jc = idx & 7;
    uint4 val = *(const uint4*)&T[d][jc*8];
    *(uint4*)(Ob + (size_t)d * 64 + jc*8) = val;
  }
}

// ---------------- histogram exclusive scan (3 stages), chunk=512 ----------------
__global__ __launch_bounds__(256) void scan1_kernel(const unsigned* __restrict__ hist,
                                                    unsigned* __restrict__ csum) {
  __shared__ unsigned sd[256];
  int c = blockIdx.x, t = threadIdx.x;
  const unsigned* p = hist + (size_t)c * 512;
  sd[t] = p[t] + p[t + 256];
  __syncthreads();
  for (int off = 128; off; off >>= 1) {
    if (t < off) sd[t] += sd[t + off];
    __syncthreads();
  }
  if (t == 0) csum[c] = sd[0];
}

__global__ __launch_bounds__(256) void scan2_kernel(unsigned* __restrict__ csum) {
  __shared__ unsigned d[256];
  int t = threadIdx.x;
  unsigned v = (t < NCHUNK) ? csum[t] : 0u;
  d[t] = v; __syncthreads();
  for (int off = 1; off < 256; off <<= 1) {
    unsigned x = (t >= off) ? d[t - off] : 0u;
    __syncthreads();
    d[t] += x;
    __syncthreads();
  }
  if (t < NCHUNK) csum[t] = d[t] - v;   // exclusive
}

// scan3: per-bin midrank -> tab2[c] = fp16(-log(prob(midrank)))
__global__ __launch_bounds__(256) void scan3_kernel(const unsigned* __restrict__ hist,
                                                    const unsigned* __restrict__ csum,
                                                    _Float16* __restrict__ tab2) {
  __shared__ unsigned ts[256];
  int c = blockIdx.x, t = threadIdx.x;
  const unsigned* p = hist + (size_t)c * 512 + t * 2;
  unsigned l0 = p[0], l1 = p[1];
  unsigned s = l0 + l1;
  ts[t] = s; __syncthreads();
  for (int off = 1; off < 256; off <<= 1) {
    unsigned x = (t >= off) ? ts[t - off] : 0u;
    __syncthreads();
    ts[t] += x;
    __syncthreads();
  }
  unsigned base = csum[c] + ts[t] - s;
  int idx = c * 512 + t * 2;
  float r0 = (float)base + 0.5f * ((float)l0 - 1.0f);
  tab2[idx]     = (_Float16)(-__logf(fmaf(r0, INV_NM1, INV_N)));
  float r1 = (float)(base + l0) + 0.5f * ((float)l1 - 1.0f);
  tab2[idx + 1] = (_Float16)(-__logf(fmaf(r1, INV_NM1, INV_N)));
}

// ---------------- fused code->P map + MFMA P.V + rowsum-normalized epilogue ----------------
// Structure = round-3/4 verified pv: 16 rows/block, 4 waves k-split, dedicated
// red exchange. NEW: reads u16 codes (half the bytes) and does pure table
// gather (no fp32 decode/clamp/zero-guard).
__global__ __launch_bounds__(256) void pv_mfma_kernel(
    const unsigned short* __restrict__ code16, const _Float16* __restrict__ Vt,
    const unsigned short* __restrict__ tab2, float* __restrict__ out) {
  __shared__ unsigned short ldsT[NPVT];   // 20480 B hot table
  __shared__ float red[4352];             // 17408 B exchange (separate object)
  int tid = threadIdx.x;
  {
    const unsigned* gsrc = (const unsigned*)(tab2 + PV_LO_C);
    unsigned* ldst = (unsigned*)ldsT;
    #pragma unroll
    for (int i = 0; i < 20; ++i)          // 20*256 uints = 10240 ushorts
      ldst[i * 256 + tid] = gsrc[i * 256 + tid];
  }
  __syncthreads();

  int bh   = blockIdx.y;
  int wave = tid >> 6;
  int lane = tid & 63;
  int m    = lane & 15;
  int quad = lane >> 4;
  int i0   = blockIdx.x * 16;
  const unsigned short* Sb = code16 + (size_t)bh * 1048576 + (size_t)(i0 + m) * 64;
  const _Float16*       Vb = Vt + (size_t)bh * 65536;
  floatx4 acc[4];
  #pragma unroll
  for (int n = 0; n < 4; ++n) acc[n] = (floatx4){0.f, 0.f, 0.f, 0.f};
  float rsum = 0.f;

  // wave w covers k in [w*256, (w+1)*256): 8 iterations of 32 cols
  for (int ks = 0; ks < 8; ++ks) {
    int k0  = wave * 256 + ks * 32 + quad * 8;
    int jt  = k0 >> 6;
    int jin = k0 & 63;
    uint4 w = *(const uint4*)(Sb + (size_t)jt * 65536 + jin);
    unsigned ww[4] = {w.x, w.y, w.z, w.w};
    union { unsigned short u[8]; half8 h; } af;
    #pragma unroll
    for (int e = 0; e < 8; ++e) {
      unsigned cd = (e & 1) ? (ww[e >> 1] >> 16) : (ww[e >> 1] & 0xffffu);
      unsigned c  = cd & 0x7fffu;
      unsigned sg = cd & 0x8000u;
      unsigned short tb;
      if (c >= PV_LO_C) tb = ldsT[c - PV_LO_C];
      else              tb = tab2[c];      // ~0.6% of lookups, L2-resident table
      af.u[e] = (unsigned short)(tb ^ sg);
      unsigned short tabs = (unsigned short)(tb & 0x7fffu);
      _Float16 th = __builtin_bit_cast(_Float16, tabs);
      rsum += (float)th;
    }
    half8 bf[4];
    #pragma unroll
    for (int n = 0; n < 4; ++n)
      bf[n] = *(const half8*)(Vb + (size_t)jt * 4096 + (size_t)(n * 16 + m) * 64 + jin);
    #pragma unroll
    for (int n = 0; n < 4; ++n)
      acc[n] = __builtin_amdgcn_mfma_f32_16x16x32_f16(af.h, bf[n], acc[n], 0, 0, 0);
  }

  // ---- cross-wave exchange into dedicated red buffer ----
  #pragma unroll
  for (int n = 0; n < 4; ++n)
    #pragma unroll
    for (int r = 0; r < 4; ++r)
      red[(wave * 16 + quad * 4 + r) * 64 + n * 16 + m] = acc[n][r];
  red[4096 + wave * 64 + lane] = rsum;   // raw per-lane rsum (row = lane&15)
  __syncthreads();

  // ---- cooperative reduce + normalize + store: 16 rows x 64 cols ----
  int col = tid & 63;
  int rq  = tid >> 6;
  #pragma unroll
  for (int t = 0; t < 4; ++t) {
    int row = rq * 4 + t;
    float s = 0.f;
    #pragma unroll
    for (int w = 0; w < 4; ++w) s += red[(w * 16 + row) * 64 + col];
    float rs = 0.f;
    #pragma unroll
    for (int w = 0; w < 4; ++w)
      #pragma unroll
      for (int q = 0; q < 4; ++q)
        rs += red[4096 + w * 64 + q * 16 + row];
    out[((size_t)bh * S_LEN + i0 + row) * D_DIM + col] = s / rs;
  }
}

// ---------------- launch ----------------
extern "C" void kernel_launch(void* const* d_in, const int* in_sizes, int n_in,
                              void* d_out, int out_size, void* d_ws, size_t ws_size,
                              hipStream_t stream) {
  const float* Q = (const float*)d_in[0];
  const float* K = (const float*)d_in[1];
  const float* V = (const float*)d_in[2];
  float* out = (float*)d_out;
  char* ws = (char*)d_ws;
  // Layout (total 71.5 MB, well under round-7-proven 142,077,952):
  //   code16 [0, 67108864)
  //   hist u32[32768] [67108864, 67239936)
  //   P2 = 67239936:
  //     partial u8 P2+0 .. +3145728            (live hist->hreduce)
  //     qinvD P2+3145728, kinvD P2+3407872     (256 KB each, live norms->qk)
  //     qinvF P2+3670016, kinvF P2+3801088     (128 KB each, live norms->qk)
  //     Vt    P2+0 .. +4194304                 (live vt->pv; aliases all of the
  //                                             above, dead after hreduce/qk)
  //     csum  P2+4194304 (256 B, scan1->scan3)
  //     tab2  P2+4195328 (65536 B, scan3->pv)
  unsigned short* code16  = (unsigned short*)(ws);
  unsigned*       hist    = (unsigned*)(ws + 67108864);
  unsigned char*  partial = (unsigned char*)(ws + 67239936);
  double*         qinvD   = (double*)(ws + 67239936 + 3145728);
  double*         kinvD   = (double*)(ws + 67239936 + 3407872);
  float*          qinvF   = (float*)(ws + 67239936 + 3670016);
  float*          kinvF   = (float*)(ws + 67239936 + 3801088);
  _Float16*       Vt      = (_Float16*)(ws + 67239936);
  unsigned*       csum    = (unsigned*)(ws + 67239936 + 4194304);
  _Float16*       tab2    = (_Float16*)(ws + 67239936 + 4195328);

  hipMemsetAsync(hist, 0, NB2 * sizeof(unsigned), stream);
  norms_kernel<<<(2 * BH * S_LEN) / 4, 256, 0, stream>>>(Q, K, qinvD, kinvD, qinvF, kinvF);
  qk_mfma_kernel<<<dim3(16, 16, BH), 256, 0, stream>>>(Q, K, qinvF, kinvF, qinvD, kinvD, code16);
  hist_kernel<<<HBLK, 1024, 0, stream>>>((const uint4*)code16, hist, partial);
  hreduce_kernel<<<NHOT_H / 256, 256, 0, stream>>>(partial, hist);
  vt_kernel<<<dim3(16, BH), 256, 0, stream>>>(V, Vt);
  scan1_kernel<<<NCHUNK, 256, 0, stream>>>(hist, csum);
  scan2_kernel<<<1, 256, 0, stream>>>(csum);
  scan3_kernel<<<NCHUNK, 256, 0, stream>>>(hist, csum, tab2);
  pv_mfma_kernel<<<dim3(S_LEN / 16, BH), 256, 0, stream>>>(
      code16, Vt, (const unsigned short*)tab2, out);
}

// Round 6
// 199.215 us; speedup vs baseline: 1.0919x; 1.0092x over previous
//
#include <hip/hip_runtime.h>
#include <math.h>
#include <stdint.h>

#define S_LEN 1024
#define D_DIM 64
#define BH    32
#define KSHIFT 13
#define NBINS 130048u             // 0x3F800000 >> 13 : |score| < 1.0, 18-bit fp32 bins
#define CODE_BASE 97280u          // bins below this (|s| < 2^-32, ~0 elems) clamp to code 0
#define NB2   32768u              // 15-bit code bins = NBINS - CODE_BASE
#define HIST_LO_C 20480u          // hist LDS window: codes for |s| >= 2^-12
#define NHOT_H  12288u            // NB2 - HIST_LO_C
#define PV_LO_C 22528u            // pv LDS table: codes for |s| >= 2^-10
#define NPVT   10240u             // NB2 - PV_LO_C
#define NCHUNK 64                 // NB2 / 512
#define HBLK   256                // hist kernel blocks (1024 thr each)
#define INV_NM1 (1.0f/33554431.0f)
#define INV_N   (2.9802322387695312e-08f)  // 1/2^25
#define FIX_TH  1e-4f             // |s| below this -> wave-coop fp64 recompute in qk (~21K elems)

// Score is stored ONLY as a u16 code: sign(bit15) | (fp32-bin - CODE_BASE).
// r5 counters: code16 is L3-resident (pv hbm_bytes ~8 MB, 173 GB/s) yet pv=48us
// with all pipes <35% -> latency-bound on the L3-hit path. VGPR=52 proves the
// ks-loop was NOT pipelined (8 serial ~500cy load exposures per wave). r6 fix:
// prefetch all 8 code loads into registers BEFORE table staging + barrier.
// Code layout is J-TILE-MAJOR: flat = ((bh*16 + jt)*1024 + i)*64 + jin.

typedef _Float16 half8 __attribute__((ext_vector_type(8)));
typedef short    short8 __attribute__((ext_vector_type(8)));
typedef float    floatx4 __attribute__((ext_vector_type(4)));

// ---------------- row norms: 1/(||row||+1e-5), fp64 + fp32 copies ----------------
__global__ __launch_bounds__(256) void norms_kernel(
    const float* __restrict__ Q, const float* __restrict__ K,
    double* __restrict__ qinvD, double* __restrict__ kinvD,
    float* __restrict__ qinvF, float* __restrict__ kinvF) {
  int row  = blockIdx.x * 4 + (threadIdx.x >> 6);
  int lane = threadIdx.x & 63;
  const float* src; double* dstD; float* dstF; int r = row;
  if (row < BH * S_LEN) { src = Q; dstD = qinvD; dstF = qinvF; }
  else                  { src = K; dstD = kinvD; dstF = kinvF; r = row - BH * S_LEN; }
  double v = (double)src[(size_t)r * D_DIM + lane];
  double s = v * v;
  #pragma unroll
  for (int off = 32; off; off >>= 1) s += __shfl_down(s, off);
  if (lane == 0) {
    double inv = 1.0 / (sqrt(s) + 1e-5);
    dstD[r] = inv;
    dstF[r] = (float)inv;
  }
}

// bf16 split helper: x -> hi (RNE) + lo (RZ of residual), as raw bf16 bit patterns
__device__ __forceinline__ void bf16_split(float x, short& hi, short& lo) {
  unsigned u = __float_as_uint(x);
  unsigned h = (u + 0x7FFFu + ((u >> 16) & 1u)) >> 16;   // RNE to bf16
  float hf = __uint_as_float(h << 16);
  float lf = x - hf;                                     // exact (Sterbenz)
  hi = (short)h;
  lo = (short)(__float_as_uint(lf) >> 16);               // RZ to bf16
}

// -------- QK^T via bf16-split MFMA + fused fp64 fixup + bin -> u16 code --------
__global__ __launch_bounds__(256) void qk_mfma_kernel(
    const float* __restrict__ Q, const float* __restrict__ K,
    const float* __restrict__ qinvF, const float* __restrict__ kinvF,
    const double* __restrict__ qinvD, const double* __restrict__ kinvD,
    unsigned short* __restrict__ code16) {
  __shared__ short Qhi[64][72], Qlo[64][72];   // stride 72 shorts = 144 B: 16B-aligned, 2-way banks
  __shared__ short Khi[64][72], Klo[64][72];
  int bh = blockIdx.z;
  int i0 = blockIdx.y * 64;
  int j0 = blockIdx.x * 64;
  int tid = threadIdx.x;
  const float* Qb = Q + ((size_t)bh * S_LEN + i0) * D_DIM;
  const float* Kb = K + ((size_t)bh * S_LEN + j0) * D_DIM;
  #pragma unroll
  for (int l = 0; l < 4; ++l) {
    int idx4 = l * 256 + tid;          // 0..1023 float4 of 64x64 tile
    int row  = idx4 >> 4;
    int c4   = idx4 & 15;
    float qi = qinvF[(size_t)bh * S_LEN + i0 + row];
    float4 v = ((const float4*)Qb)[idx4];
    float qv[4] = {v.x * qi, v.y * qi, v.z * qi, v.w * qi};
    short qh[4], ql[4];
    #pragma unroll
    for (int c = 0; c < 4; ++c) bf16_split(qv[c], qh[c], ql[c]);
    *(short4*)&Qhi[row][c4 * 4] = make_short4(qh[0], qh[1], qh[2], qh[3]);
    *(short4*)&Qlo[row][c4 * 4] = make_short4(ql[0], ql[1], ql[2], ql[3]);
    float kj = kinvF[(size_t)bh * S_LEN + j0 + row];
    float4 w = ((const float4*)Kb)[idx4];
    float kv[4] = {w.x * kj, w.y * kj, w.z * kj, w.w * kj};
    short kh[4], kl[4];
    #pragma unroll
    for (int c = 0; c < 4; ++c) bf16_split(kv[c], kh[c], kl[c]);
    *(short4*)&Khi[row][c4 * 4] = make_short4(kh[0], kh[1], kh[2], kh[3]);
    *(short4*)&Klo[row][c4 * 4] = make_short4(kl[0], kl[1], kl[2], kl[3]);
  }
  __syncthreads();
  int wave = tid >> 6;
  int lane = tid & 63;
  int m    = lane & 15;
  int quad = lane >> 4;
  floatx4 acc[4];
  #pragma unroll
  for (int n = 0; n < 4; ++n) acc[n] = (floatx4){0.f, 0.f, 0.f, 0.f};
  #pragma unroll
  for (int ks = 0; ks < 2; ++ks) {
    int kb = ks * 32 + quad * 8;
    short8 a_hi = *(const short8*)&Qhi[wave * 16 + m][kb];
    short8 a_lo = *(const short8*)&Qlo[wave * 16 + m][kb];
    #pragma unroll
    for (int nt = 0; nt < 4; ++nt) {
      short8 b_hi = *(const short8*)&Khi[nt * 16 + m][kb];
      short8 b_lo = *(const short8*)&Klo[nt * 16 + m][kb];
      acc[nt] = __builtin_amdgcn_mfma_f32_16x16x32_bf16(a_hi, b_hi, acc[nt], 0, 0, 0);
      acc[nt] = __builtin_amdgcn_mfma_f32_16x16x32_bf16(a_hi, b_lo, acc[nt], 0, 0, 0);
      acc[nt] = __builtin_amdgcn_mfma_f32_16x16x32_bf16(a_lo, b_hi, acc[nt], 0, 0, 0);
    }
  }
  // ---- rare fp64 fixup (wave-cooperative), fused ----
  // lane (quad,m) slot (nt,r): i = i0+wave*16+quad*4+r, j = j0+nt*16+m
  #pragma unroll
  for (int nt = 0; nt < 4; ++nt) {
    #pragma unroll
    for (int r = 0; r < 4; ++r) {
      unsigned long long am = __ballot(fabsf(acc[nt][r]) < FIX_TH);
      while (am) {
        int src = (int)(__ffsll((long long)am) - 1);
        am &= am - 1;
        int i_s = i0 + wave * 16 + (src >> 4) * 4 + r;
        int j_s = j0 + nt * 16 + (src & 15);
        double qd = (double)Q[((size_t)bh * S_LEN + i_s) * D_DIM + lane];
        double kd = (double)K[((size_t)bh * S_LEN + j_s) * D_DIM + lane];
        double pd = qd * kd;
        #pragma unroll
        for (int off = 32; off; off >>= 1) pd += __shfl_down(pd, off);
        float corr = 0.f;
        if (lane == 0)
          corr = (float)(pd * qinvD[(size_t)bh * S_LEN + i_s] * kinvD[(size_t)bh * S_LEN + j_s]);
        corr = __shfl(corr, 0);
        if (lane == src) acc[nt][r] = corr;
      }
    }
  }
  // ---- bin + store u16 codes, tile-major ----
  // C/D: row = quad*4 + r, col = lane&15; flat = bh*2^20 + jt*65536 + i*64 + jin
  #pragma unroll
  for (int r = 0; r < 4; ++r) {
    unsigned short* op = code16 + (size_t)bh * 1048576 + (size_t)(j0 >> 6) * 65536
                       + (size_t)(i0 + wave * 16 + quad * 4 + r) * 64 + m;
    #pragma unroll
    for (int nt = 0; nt < 4; ++nt) {
      unsigned u = __float_as_uint(acc[nt][r]);
      unsigned a = u & 0x7fffffffu;
      unsigned b = a >> KSHIFT;
      if (b > NBINS - 1u) b = NBINS - 1u;
      unsigned c = (b < CODE_BASE) ? 0u : (b - CODE_BASE);
      op[nt * 16] = (unsigned short)(c | ((u >> 16) & 0x8000u));
    }
  }
}

// ---------------- histogram: pure code streamer (LDS hot window) ----------------
__global__ __launch_bounds__(1024) void hist_kernel(
    const uint4* __restrict__ codes, unsigned* __restrict__ hist,
    unsigned char* __restrict__ partial) {
  __shared__ unsigned lh[NHOT_H];
  int tid = threadIdx.x;
  for (unsigned i = tid; i < NHOT_H; i += 1024) lh[i] = 0u;
  __syncthreads();
  // 2^25 u16 codes = 4,194,304 uint4; 16384 per block; 16 iters of 1024 threads
  const uint4* p = codes + (size_t)blockIdx.x * 16384;
  #pragma unroll 2
  for (int it = 0; it < 16; ++it) {
    uint4 w = p[it * 1024 + tid];
    unsigned ws[4] = {w.x, w.y, w.z, w.w};
    #pragma unroll
    for (int k = 0; k < 4; ++k) {
      unsigned c0 = ws[k] & 0x7fffu;
      unsigned c1 = (ws[k] >> 16) & 0x7fffu;
      if (c0 >= HIST_LO_C) atomicAdd(&lh[c0 - HIST_LO_C], 1u);
      else                 atomicAdd(&hist[c0], 1u);    // rare (~1.6e-3)
      if (c1 >= HIST_LO_C) atomicAdd(&lh[c1 - HIST_LO_C], 1u);
      else                 atomicAdd(&hist[c1], 1u);
    }
  }
  __syncthreads();
  unsigned char* dst = partial + (size_t)blockIdx.x * NHOT_H;
  for (unsigned i = tid; i < NHOT_H; i += 1024) dst[i] = (unsigned char)lh[i];
}

// ---------------- reduce u8 partial histograms into hist hot range ----------------
__global__ __launch_bounds__(256) void hreduce_kernel(
    const unsigned char* __restrict__ partial, unsigned* __restrict__ hist) {
  unsigned bin = blockIdx.x * 256 + threadIdx.x;   // 48 blocks * 256 = 12288
  unsigned s = 0;
  #pragma unroll 8
  for (int b = 0; b < HBLK; ++b) s += (unsigned)partial[(size_t)b * NHOT_H + bin];
  hist[HIST_LO_C + bin] = s;
}

// ---------------- V (fp32 [j][d]) -> Vt tiled fp16 [jt][d][jin] ----------------
__global__ __launch_bounds__(256) void vt_kernel(
    const float* __restrict__ V, _Float16* __restrict__ Vt) {
  __shared__ _Float16 T[64][72];
  int bh = blockIdx.y, j0 = blockIdx.x * 64, tid = threadIdx.x;
  const float* Vb = V + ((size_t)bh * S_LEN + j0) * D_DIM;
  #pragma unroll
  for (int l = 0; l < 4; ++l) {
    int idx = l * 256 + tid;
    int jr = idx >> 4, d4 = idx & 15;
    float4 v = ((const float4*)Vb)[idx];
    T[d4*4+0][jr] = (_Float16)v.x;
    T[d4*4+1][jr] = (_Float16)v.y;
    T[d4*4+2][jr] = (_Float16)v.z;
    T[d4*4+3][jr] = (_Float16)v.w;
  }
  __syncthreads();
  _Float16* Ob = Vt + (size_t)(bh * 16 + blockIdx.x) * 4096;
  #pragma unroll
  for (int l = 0; l < 2; ++l) {
    int idx = l * 256 + tid;
    int d = idx >> 3, jc = idx & 7;
    uint4 val = *(const uint4*)&T[d][jc*8];
    *(uint4*)(Ob + (size_t)d * 64 + jc*8) = val;
  }
}

// ---------------- histogram exclusive scan (3 stages), chunk=512 ----------------
__global__ __launch_bounds__(256) void scan1_kernel(const unsigned* __restrict__ hist,
                                                    unsigned* __restrict__ csum) {
  __shared__ unsigned sd[256];
  int c = blockIdx.x, t = threadIdx.x;
  const unsigned* p = hist + (size_t)c * 512;
  sd[t] = p[t] + p[t + 256];
  __syncthreads();
  for (int off = 128; off; off >>= 1) {
    if (t < off) sd[t] += sd[t + off];
    __syncthreads();
  }
  if (t == 0) csum[c] = sd[0];
}

__global__ __launch_bounds__(256) void scan2_kernel(unsigned* __restrict__ csum) {
  __shared__ unsigned d[256];
  int t = threadIdx.x;
  unsigned v = (t < NCHUNK) ? csum[t] : 0u;
  d[t] = v; __syncthreads();
  for (int off = 1; off < 256; off <<= 1) {
    unsigned x = (t >= off) ? d[t - off] : 0u;
    __syncthreads();
    d[t] += x;
    __syncthreads();
  }
  if (t < NCHUNK) csum[t] = d[t] - v;   // exclusive
}

// scan3: per-bin midrank -> tab2[c] = fp16(-log(prob(midrank)))
__global__ __launch_bounds__(256) void scan3_kernel(const unsigned* __restrict__ hist,
                                                    const unsigned* __restrict__ csum,
                                                    _Float16* __restrict__ tab2) {
  __shared__ unsigned ts[256];
  int c = blockIdx.x, t = threadIdx.x;
  const unsigned* p = hist + (size_t)c * 512 + t * 2;
  unsigned l0 = p[0], l1 = p[1];
  unsigned s = l0 + l1;
  ts[t] = s; __syncthreads();
  for (int off = 1; off < 256; off <<= 1) {
    unsigned x = (t >= off) ? ts[t - off] : 0u;
    __syncthreads();
    ts[t] += x;
    __syncthreads();
  }
  unsigned base = csum[c] + ts[t] - s;
  int idx = c * 512 + t * 2;
  float r0 = (float)base + 0.5f * ((float)l0 - 1.0f);
  tab2[idx]     = (_Float16)(-__logf(fmaf(r0, INV_NM1, INV_N)));
  float r1 = (float)(base + l0) + 0.5f * ((float)l1 - 1.0f);
  tab2[idx + 1] = (_Float16)(-__logf(fmaf(r1, INV_NM1, INV_N)));
}

// ---------------- fused code->P map + MFMA P.V + rowsum-normalized epilogue ----------------
// Structure = round-5 verified pv (16 rows/block, 4-wave k-split, dedicated red
// exchange). NEW (r6): all 8 code16 loads issued upfront into a fully-unrolled
// register array BEFORE table staging + barrier -> one latency exposure per
// wave instead of eight (r5: VGPR=52 proved no pipelining; latency-bound at
// 48us with all pipes <35%). Compute loop fully unrolled for Vt-load hoisting.
__global__ __launch_bounds__(256) void pv_mfma_kernel(
    const unsigned short* __restrict__ code16, const _Float16* __restrict__ Vt,
    const unsigned short* __restrict__ tab2, float* __restrict__ out) {
  __shared__ unsigned short ldsT[NPVT];   // 20480 B hot table
  __shared__ float red[4352];             // 17408 B exchange (separate object)
  int tid = threadIdx.x;

  int bh   = blockIdx.y;
  int wave = tid >> 6;
  int lane = tid & 63;
  int m    = lane & 15;
  int quad = lane >> 4;
  int i0   = blockIdx.x * 16;
  const unsigned short* Sb = code16 + (size_t)bh * 1048576 + (size_t)(i0 + m) * 64;
  const _Float16*       Vb = Vt + (size_t)bh * 65536;

  // ---- prefetch ALL 8 code vectors first: latency overlaps table staging ----
  uint4 cw[8];
  #pragma unroll
  for (int ks = 0; ks < 8; ++ks) {
    int k0  = wave * 256 + ks * 32 + quad * 8;
    int jt  = k0 >> 6;
    int jin = k0 & 63;
    cw[ks] = *(const uint4*)(Sb + (size_t)jt * 65536 + jin);
  }

  // ---- stage hot table to LDS (global loads overlap the code prefetch) ----
  {
    const unsigned* gsrc = (const unsigned*)(tab2 + PV_LO_C);
    unsigned* ldst = (unsigned*)ldsT;
    #pragma unroll
    for (int i = 0; i < 20; ++i)          // 20*256 uints = 10240 ushorts
      ldst[i * 256 + tid] = gsrc[i * 256 + tid];
  }
  __syncthreads();

  floatx4 acc[4];
  #pragma unroll
  for (int n = 0; n < 4; ++n) acc[n] = (floatx4){0.f, 0.f, 0.f, 0.f};
  float rsum = 0.f;

  // wave w covers k in [w*256, (w+1)*256): 8 unrolled steps of 32 cols
  #pragma unroll
  for (int ks = 0; ks < 8; ++ks) {
    int k0  = wave * 256 + ks * 32 + quad * 8;
    int jt  = k0 >> 6;
    int jin = k0 & 63;
    unsigned ww[4] = {cw[ks].x, cw[ks].y, cw[ks].z, cw[ks].w};
    union { unsigned short u[8]; half8 h; } af;
    #pragma unroll
    for (int e = 0; e < 8; ++e) {
      unsigned cd = (e & 1) ? (ww[e >> 1] >> 16) : (ww[e >> 1] & 0xffffu);
      unsigned c  = cd & 0x7fffu;
      unsigned sg = cd & 0x8000u;
      unsigned short tb;
      if (c >= PV_LO_C) tb = ldsT[c - PV_LO_C];
      else              tb = tab2[c];      // ~0.6% of lookups, L2-resident table
      af.u[e] = (unsigned short)(tb ^ sg);
      unsigned short tabs = (unsigned short)(tb & 0x7fffu);
      _Float16 th = __builtin_bit_cast(_Float16, tabs);
      rsum += (float)th;
    }
    half8 bf[4];
    #pragma unroll
    for (int n = 0; n < 4; ++n)
      bf[n] = *(const half8*)(Vb + (size_t)jt * 4096 + (size_t)(n * 16 + m) * 64 + jin);
    #pragma unroll
    for (int n = 0; n < 4; ++n)
      acc[n] = __builtin_amdgcn_mfma_f32_16x16x32_f16(af.h, bf[n], acc[n], 0, 0, 0);
  }

  // ---- cross-wave exchange into dedicated red buffer ----
  #pragma unroll
  for (int n = 0; n < 4; ++n)
    #pragma unroll
    for (int r = 0; r < 4; ++r)
      red[(wave * 16 + quad * 4 + r) * 64 + n * 16 + m] = acc[n][r];
  red[4096 + wave * 64 + lane] = rsum;   // raw per-lane rsum (row = lane&15)
  __syncthreads();

  // ---- cooperative reduce + normalize + store: 16 rows x 64 cols ----
  int col = tid & 63;
  int rq  = tid >> 6;
  #pragma unroll
  for (int t = 0; t < 4; ++t) {
    int row = rq * 4 + t;
    float s = 0.f;
    #pragma unroll
    for (int w = 0; w < 4; ++w) s += red[(w * 16 + row) * 64 + col];
    float rs = 0.f;
    #pragma unroll
    for (int w = 0; w < 4; ++w)
      #pragma unroll
      for (int q = 0; q < 4; ++q)
        rs += red[4096 + w * 64 + q * 16 + row];
    out[((size_t)bh * S_LEN + i0 + row) * D_DIM + col] = s / rs;
  }
}

// ---------------- launch ----------------
extern "C" void kernel_launch(void* const* d_in, const int* in_sizes, int n_in,
                              void* d_out, int out_size, void* d_ws, size_t ws_size,
                              hipStream_t stream) {
  const float* Q = (const float*)d_in[0];
  const float* K = (const float*)d_in[1];
  const float* V = (const float*)d_in[2];
  float* out = (float*)d_out;
  char* ws = (char*)d_ws;
  // Layout (total 71.5 MB):
  //   code16 [0, 67108864)
  //   hist u32[32768] [67108864, 67239936)
  //   P2 = 67239936:
  //     partial u8 P2+0 .. +3145728            (live hist->hreduce)
  //     qinvD P2+3145728, kinvD P2+3407872     (256 KB each, live norms->qk)
  //     qinvF P2+3670016, kinvF P2+3801088     (128 KB each, live norms->qk)
  //     Vt    P2+0 .. +4194304                 (live vt->pv; aliases the above, all dead)
  //     csum  P2+4194304 (256 B, scan1->scan3)
  //     tab2  P2+4195328 (65536 B, scan3->pv)
  unsigned short* code16  = (unsigned short*)(ws);
  unsigned*       hist    = (unsigned*)(ws + 67108864);
  unsigned char*  partial = (unsigned char*)(ws + 67239936);
  double*         qinvD   = (double*)(ws + 67239936 + 3145728);
  double*         kinvD   = (double*)(ws + 67239936 + 3407872);
  float*          qinvF   = (float*)(ws + 67239936 + 3670016);
  float*          kinvF   = (float*)(ws + 67239936 + 3801088);
  _Float16*       Vt      = (_Float16*)(ws + 67239936);
  unsigned*       csum    = (unsigned*)(ws + 67239936 + 4194304);
  _Float16*       tab2    = (_Float16*)(ws + 67239936 + 4195328);

  hipMemsetAsync(hist, 0, NB2 * sizeof(unsigned), stream);
  norms_kernel<<<(2 * BH * S_LEN) / 4, 256, 0, stream>>>(Q, K, qinvD, kinvD, qinvF, kinvF);
  qk_mfma_kernel<<<dim3(16, 16, BH), 256, 0, stream>>>(Q, K, qinvF, kinvF, qinvD, kinvD, code16);
  hist_kernel<<<HBLK, 1024, 0, stream>>>((const uint4*)code16, hist, partial);
  hreduce_kernel<<<NHOT_H / 256, 256, 0, stream>>>(partial, hist);
  vt_kernel<<<dim3(16, BH), 256, 0, stream>>>(V, Vt);
  scan1_kernel<<<NCHUNK, 256, 0, stream>>>(hist, csum);
  scan2_kernel<<<1, 256, 0, stream>>>(csum);
  scan3_kernel<<<NCHUNK, 256, 0, stream>>>(hist, csum, tab2);
  pv_mfma_kernel<<<dim3(S_LEN / 16, BH), 256, 0, stream>>>(
      code16, Vt, (const unsigned short*)tab2, out);
}

// Round 7
// 198.277 us; speedup vs baseline: 1.0970x; 1.0047x over previous
//
#include <hip/hip_runtime.h>
#include <math.h>
#include <stdint.h>

#define S_LEN 1024
#define D_DIM 64
#define BH    32
#define KSHIFT 13
#define NBINS 130048u             // 0x3F800000 >> 13 : |score| < 1.0, 18-bit fp32 bins
#define CODE_BASE 97280u          // bins below this (|s| < 2^-32, ~0 elems) clamp to code 0
#define NB2   32768u              // 15-bit code bins = NBINS - CODE_BASE
#define HIST_LO_C 20480u          // hist LDS window: codes for |s| >= 2^-12
#define NHOT_H  12288u            // NB2 - HIST_LO_C
#define PV_LO_C 22528u            // pv LDS table: codes for |s| >= 2^-10
#define NPVT   10240u             // NB2 - PV_LO_C
#define NCHUNK 64                 // NB2 / 512
#define HBLK   256                // hist kernel blocks (1024 thr each)
#define INV_NM1 (1.0f/33554431.0f)
#define INV_N   (2.9802322387695312e-08f)  // 1/2^25
#define FIX_TH  1e-4f             // |s| below this -> wave-coop fp64 recompute in qk (~21K elems)

// r6 counters: qk = 54us, VALUBusy 45%, MfmaUtil 9% -> VALU-bound on staging:
// every block re-split its Q/K tiles to bf16 hi/lo (~200 VALU/thread), and each
// tile is re-split 16x across j0/i0 blocks. r7: normalize+split ONCE in norms
// (which already reads all of Q/K), store Qhi/Qlo/Khi/Klo as global bf16
// arrays (4 MB each, L3-resident); qk stages them with plain uint4 copies.
// Arithmetic identical at every step -> codes bit-identical.

typedef _Float16 half8 __attribute__((ext_vector_type(8)));
typedef short    short8 __attribute__((ext_vector_type(8)));
typedef float    floatx4 __attribute__((ext_vector_type(4)));

// bf16 split helper: x -> hi (RNE) + lo (RZ of residual), as raw bf16 bit patterns
__device__ __forceinline__ void bf16_split(float x, short& hi, short& lo) {
  unsigned u = __float_as_uint(x);
  unsigned h = (u + 0x7FFFu + ((u >> 16) & 1u)) >> 16;   // RNE to bf16
  float hf = __uint_as_float(h << 16);
  float lf = x - hf;                                     // exact (Sterbenz)
  hi = (short)h;
  lo = (short)(__float_as_uint(lf) >> 16);               // RZ to bf16
}

// ------- row norms + fused normalize/bf16-split: 1/(||row||+1e-5) -------
__global__ __launch_bounds__(256) void norms_kernel(
    const float* __restrict__ Q, const float* __restrict__ K,
    double* __restrict__ qinvD, double* __restrict__ kinvD,
    unsigned short* __restrict__ Qhi_g, unsigned short* __restrict__ Qlo_g,
    unsigned short* __restrict__ Khi_g, unsigned short* __restrict__ Klo_g) {
  int row  = blockIdx.x * 4 + (threadIdx.x >> 6);
  int lane = threadIdx.x & 63;
  const float* src; double* dstD; unsigned short *hD, *lD; int r = row;
  if (row < BH * S_LEN) { src = Q; dstD = qinvD; hD = Qhi_g; lD = Qlo_g; }
  else { src = K; dstD = kinvD; hD = Khi_g; lD = Klo_g; r = row - BH * S_LEN; }
  float xf = src[(size_t)r * D_DIM + lane];
  double v = (double)xf;
  double s = v * v;
  #pragma unroll
  for (int off = 32; off; off >>= 1) s += __shfl_down(s, off);
  double inv = 0.0;
  if (lane == 0) {
    inv = 1.0 / (sqrt(s) + 1e-5);
    dstD[r] = inv;
  }
  inv = __shfl(inv, 0);
  float x = xf * (float)inv;      // identical rounding to old qk's v.x * qinvF[row]
  short hi, lo;
  bf16_split(x, hi, lo);
  hD[(size_t)r * D_DIM + lane] = (unsigned short)hi;
  lD[(size_t)r * D_DIM + lane] = (unsigned short)lo;
}

// -------- QK^T via pre-split bf16 MFMA + fused fp64 fixup + bin -> u16 code --------
__global__ __launch_bounds__(256) void qk_mfma_kernel(
    const float* __restrict__ Q, const float* __restrict__ K,
    const unsigned short* __restrict__ Qhi_g, const unsigned short* __restrict__ Qlo_g,
    const unsigned short* __restrict__ Khi_g, const unsigned short* __restrict__ Klo_g,
    const double* __restrict__ qinvD, const double* __restrict__ kinvD,
    unsigned short* __restrict__ code16) {
  __shared__ short Qhi[64][72], Qlo[64][72];   // stride 72 shorts = 144 B: 16B-aligned, 2-way banks
  __shared__ short Khi[64][72], Klo[64][72];
  int bh = blockIdx.z;
  int i0 = blockIdx.y * 64;
  int j0 = blockIdx.x * 64;
  int tid = threadIdx.x;
  // ---- stage pre-split tiles: 8 uint4 copies per thread (no VALU split work) ----
  {
    const unsigned short* Qh = Qhi_g + ((size_t)bh * S_LEN + i0) * D_DIM;
    const unsigned short* Ql = Qlo_g + ((size_t)bh * S_LEN + i0) * D_DIM;
    const unsigned short* Kh = Khi_g + ((size_t)bh * S_LEN + j0) * D_DIM;
    const unsigned short* Kl = Klo_g + ((size_t)bh * S_LEN + j0) * D_DIM;
    #pragma unroll
    for (int l = 0; l < 2; ++l) {
      int idx = l * 256 + tid;          // 0..511 : row = idx>>3, col8 = (idx&7)*8
      int row = idx >> 3, c = (idx & 7) * 8;
      *(uint4*)&Qhi[row][c] = *(const uint4*)(Qh + (size_t)row * D_DIM + c);
      *(uint4*)&Qlo[row][c] = *(const uint4*)(Ql + (size_t)row * D_DIM + c);
      *(uint4*)&Khi[row][c] = *(const uint4*)(Kh + (size_t)row * D_DIM + c);
      *(uint4*)&Klo[row][c] = *(const uint4*)(Kl + (size_t)row * D_DIM + c);
    }
  }
  __syncthreads();
  int wave = tid >> 6;
  int lane = tid & 63;
  int m    = lane & 15;
  int quad = lane >> 4;
  floatx4 acc[4];
  #pragma unroll
  for (int n = 0; n < 4; ++n) acc[n] = (floatx4){0.f, 0.f, 0.f, 0.f};
  #pragma unroll
  for (int ks = 0; ks < 2; ++ks) {
    int kb = ks * 32 + quad * 8;
    short8 a_hi = *(const short8*)&Qhi[wave * 16 + m][kb];
    short8 a_lo = *(const short8*)&Qlo[wave * 16 + m][kb];
    #pragma unroll
    for (int nt = 0; nt < 4; ++nt) {
      short8 b_hi = *(const short8*)&Khi[nt * 16 + m][kb];
      short8 b_lo = *(const short8*)&Klo[nt * 16 + m][kb];
      acc[nt] = __builtin_amdgcn_mfma_f32_16x16x32_bf16(a_hi, b_hi, acc[nt], 0, 0, 0);
      acc[nt] = __builtin_amdgcn_mfma_f32_16x16x32_bf16(a_hi, b_lo, acc[nt], 0, 0, 0);
      acc[nt] = __builtin_amdgcn_mfma_f32_16x16x32_bf16(a_lo, b_hi, acc[nt], 0, 0, 0);
    }
  }
  // ---- rare fp64 fixup (wave-cooperative), fused ----
  // lane (quad,m) slot (nt,r): i = i0+wave*16+quad*4+r, j = j0+nt*16+m
  #pragma unroll
  for (int nt = 0; nt < 4; ++nt) {
    #pragma unroll
    for (int r = 0; r < 4; ++r) {
      unsigned long long am = __ballot(fabsf(acc[nt][r]) < FIX_TH);
      while (am) {
        int src = (int)(__ffsll((long long)am) - 1);
        am &= am - 1;
        int i_s = i0 + wave * 16 + (src >> 4) * 4 + r;
        int j_s = j0 + nt * 16 + (src & 15);
        double qd = (double)Q[((size_t)bh * S_LEN + i_s) * D_DIM + lane];
        double kd = (double)K[((size_t)bh * S_LEN + j_s) * D_DIM + lane];
        double pd = qd * kd;
        #pragma unroll
        for (int off = 32; off; off >>= 1) pd += __shfl_down(pd, off);
        float corr = 0.f;
        if (lane == 0)
          corr = (float)(pd * qinvD[(size_t)bh * S_LEN + i_s] * kinvD[(size_t)bh * S_LEN + j_s]);
        corr = __shfl(corr, 0);
        if (lane == src) acc[nt][r] = corr;
      }
    }
  }
  // ---- bin + store u16 codes, tile-major ----
  // C/D: row = quad*4 + r, col = lane&15; flat = bh*2^20 + jt*65536 + i*64 + jin
  #pragma unroll
  for (int r = 0; r < 4; ++r) {
    unsigned short* op = code16 + (size_t)bh * 1048576 + (size_t)(j0 >> 6) * 65536
                       + (size_t)(i0 + wave * 16 + quad * 4 + r) * 64 + m;
    #pragma unroll
    for (int nt = 0; nt < 4; ++nt) {
      unsigned u = __float_as_uint(acc[nt][r]);
      unsigned a = u & 0x7fffffffu;
      unsigned b = a >> KSHIFT;
      if (b > NBINS - 1u) b = NBINS - 1u;
      unsigned c = (b < CODE_BASE) ? 0u : (b - CODE_BASE);
      op[nt * 16] = (unsigned short)(c | ((u >> 16) & 0x8000u));
    }
  }
}

// ---------------- histogram: pure code streamer (LDS hot window) ----------------
__global__ __launch_bounds__(1024) void hist_kernel(
    const uint4* __restrict__ codes, unsigned* __restrict__ hist,
    unsigned char* __restrict__ partial) {
  __shared__ unsigned lh[NHOT_H];
  int tid = threadIdx.x;
  for (unsigned i = tid; i < NHOT_H; i += 1024) lh[i] = 0u;
  __syncthreads();
  // 2^25 u16 codes = 4,194,304 uint4; 16384 per block; 16 iters of 1024 threads
  const uint4* p = codes + (size_t)blockIdx.x * 16384;
  #pragma unroll 2
  for (int it = 0; it < 16; ++it) {
    uint4 w = p[it * 1024 + tid];
    unsigned ws[4] = {w.x, w.y, w.z, w.w};
    #pragma unroll
    for (int k = 0; k < 4; ++k) {
      unsigned c0 = ws[k] & 0x7fffu;
      unsigned c1 = (ws[k] >> 16) & 0x7fffu;
      if (c0 >= HIST_LO_C) atomicAdd(&lh[c0 - HIST_LO_C], 1u);
      else                 atomicAdd(&hist[c0], 1u);    // rare (~1.6e-3)
      if (c1 >= HIST_LO_C) atomicAdd(&lh[c1 - HIST_LO_C], 1u);
      else                 atomicAdd(&hist[c1], 1u);
    }
  }
  __syncthreads();
  unsigned char* dst = partial + (size_t)blockIdx.x * NHOT_H;
  for (unsigned i = tid; i < NHOT_H; i += 1024) dst[i] = (unsigned char)lh[i];
}

// ---------------- reduce u8 partial histograms into hist hot range ----------------
__global__ __launch_bounds__(256) void hreduce_kernel(
    const unsigned char* __restrict__ partial, unsigned* __restrict__ hist) {
  unsigned bin = blockIdx.x * 256 + threadIdx.x;   // 48 blocks * 256 = 12288
  unsigned s = 0;
  #pragma unroll 8
  for (int b = 0; b < HBLK; ++b) s += (unsigned)partial[(size_t)b * NHOT_H + bin];
  hist[HIST_LO_C + bin] = s;
}

// ---------------- V (fp32 [j][d]) -> Vt tiled fp16 [jt][d][jin] ----------------
__global__ __launch_bounds__(256) void vt_kernel(
    const float* __restrict__ V, _Float16* __restrict__ Vt) {
  __shared__ _Float16 T[64][72];
  int bh = blockIdx.y, j0 = blockIdx.x * 64, tid = threadIdx.x;
  const float* Vb = V + ((size_t)bh * S_LEN + j0) * D_DIM;
  #pragma unroll
  for (int l = 0; l < 4; ++l) {
    int idx = l * 256 + tid;
    int jr = idx >> 4, d4 = idx & 15;
    float4 v = ((const float4*)Vb)[idx];
    T[d4*4+0][jr] = (_Float16)v.x;
    T[d4*4+1][jr] = (_Float16)v.y;
    T[d4*4+2][jr] = (_Float16)v.z;
    T[d4*4+3][jr] = (_Float16)v.w;
  }
  __syncthreads();
  _Float16* Ob = Vt + (size_t)(bh * 16 + blockIdx.x) * 4096;
  #pragma unroll
  for (int l = 0; l < 2; ++l) {
    int idx = l * 256 + tid;
    int d = idx >> 3, jc = idx & 7;
    uint4 val = *(const uint4*)&T[d][jc*8];
    *(uint4*)(Ob + (size_t)d * 64 + jc*8) = val;
  }
}

// ---------------- histogram exclusive scan (3 stages), chunk=512 ----------------
__global__ __launch_bounds__(256) void scan1_kernel(const unsigned* __restrict__ hist,
                                                    unsigned* __restrict__ csum) {
  __shared__ unsigned sd[256];
  int c = blockIdx.x, t = threadIdx.x;
  const unsigned* p = hist + (size_t)c * 512;
  sd[t] = p[t] + p[t + 256];
  __syncthreads();
  for (int off = 128; off; off >>= 1) {
    if (t < off) sd[t] += sd[t + off];
    __syncthreads();
  }
  if (t == 0) csum[c] = sd[0];
}

__global__ __launch_bounds__(256) void scan2_kernel(unsigned* __restrict__ csum) {
  __shared__ unsigned d[256];
  int t = threadIdx.x;
  unsigned v = (t < NCHUNK) ? csum[t] : 0u;
  d[t] = v; __syncthreads();
  for (int off = 1; off < 256; off <<= 1) {
    unsigned x = (t >= off) ? d[t - off] : 0u;
    __syncthreads();
    d[t] += x;
    __syncthreads();
  }
  if (t < NCHUNK) csum[t] = d[t] - v;   // exclusive
}

// scan3: per-bin midrank -> tab2[c] = fp16(-log(prob(midrank)))
__global__ __launch_bounds__(256) void scan3_kernel(const unsigned* __restrict__ hist,
                                                    const unsigned* __restrict__ csum,
                                                    _Float16* __restrict__ tab2) {
  __shared__ unsigned ts[256];
  int c = blockIdx.x, t = threadIdx.x;
  const unsigned* p = hist + (size_t)c * 512 + t * 2;
  unsigned l0 = p[0], l1 = p[1];
  unsigned s = l0 + l1;
  ts[t] = s; __syncthreads();
  for (int off = 1; off < 256; off <<= 1) {
    unsigned x = (t >= off) ? ts[t - off] : 0u;
    __syncthreads();
    ts[t] += x;
    __syncthreads();
  }
  unsigned base = csum[c] + ts[t] - s;
  int idx = c * 512 + t * 2;
  float r0 = (float)base + 0.5f * ((float)l0 - 1.0f);
  tab2[idx]     = (_Float16)(-__logf(fmaf(r0, INV_NM1, INV_N)));
  float r1 = (float)(base + l0) + 0.5f * ((float)l1 - 1.0f);
  tab2[idx + 1] = (_Float16)(-__logf(fmaf(r1, INV_NM1, INV_N)));
}

// ---------------- fused code->P map + MFMA P.V + rowsum-normalized epilogue ----------------
// r6 verified: 16 rows/block, 4-wave k-split, 8 code loads prefetched into regs
// before table staging + barrier (one latency exposure per wave).
__global__ __launch_bounds__(256) void pv_mfma_kernel(
    const unsigned short* __restrict__ code16, const _Float16* __restrict__ Vt,
    const unsigned short* __restrict__ tab2, float* __restrict__ out) {
  __shared__ unsigned short ldsT[NPVT];   // 20480 B hot table
  __shared__ float red[4352];             // 17408 B exchange (separate object)
  int tid = threadIdx.x;

  int bh   = blockIdx.y;
  int wave = tid >> 6;
  int lane = tid & 63;
  int m    = lane & 15;
  int quad = lane >> 4;
  int i0   = blockIdx.x * 16;
  const unsigned short* Sb = code16 + (size_t)bh * 1048576 + (size_t)(i0 + m) * 64;
  const _Float16*       Vb = Vt + (size_t)bh * 65536;

  // ---- prefetch ALL 8 code vectors first: latency overlaps table staging ----
  uint4 cw[8];
  #pragma unroll
  for (int ks = 0; ks < 8; ++ks) {
    int k0  = wave * 256 + ks * 32 + quad * 8;
    int jt  = k0 >> 6;
    int jin = k0 & 63;
    cw[ks] = *(const uint4*)(Sb + (size_t)jt * 65536 + jin);
  }

  // ---- stage hot table to LDS (global loads overlap the code prefetch) ----
  {
    const unsigned* gsrc = (const unsigned*)(tab2 + PV_LO_C);
    unsigned* ldst = (unsigned*)ldsT;
    #pragma unroll
    for (int i = 0; i < 20; ++i)          // 20*256 uints = 10240 ushorts
      ldst[i * 256 + tid] = gsrc[i * 256 + tid];
  }
  __syncthreads();

  floatx4 acc[4];
  #pragma unroll
  for (int n = 0; n < 4; ++n) acc[n] = (floatx4){0.f, 0.f, 0.f, 0.f};
  float rsum = 0.f;

  // wave w covers k in [w*256, (w+1)*256): 8 unrolled steps of 32 cols
  #pragma unroll
  for (int ks = 0; ks < 8; ++ks) {
    int k0  = wave * 256 + ks * 32 + quad * 8;
    int jt  = k0 >> 6;
    int jin = k0 & 63;
    unsigned ww[4] = {cw[ks].x, cw[ks].y, cw[ks].z, cw[ks].w};
    union { unsigned short u[8]; half8 h; } af;
    #pragma unroll
    for (int e = 0; e < 8; ++e) {
      unsigned cd = (e & 1) ? (ww[e >> 1] >> 16) : (ww[e >> 1] & 0xffffu);
      unsigned c  = cd & 0x7fffu;
      unsigned sg = cd & 0x8000u;
      unsigned short tb;
      if (c >= PV_LO_C) tb = ldsT[c - PV_LO_C];
      else              tb = tab2[c];      // ~0.6% of lookups, L2-resident table
      af.u[e] = (unsigned short)(tb ^ sg);
      unsigned short tabs = (unsigned short)(tb & 0x7fffu);
      _Float16 th = __builtin_bit_cast(_Float16, tabs);
      rsum += (float)th;
    }
    half8 bf[4];
    #pragma unroll
    for (int n = 0; n < 4; ++n)
      bf[n] = *(const half8*)(Vb + (size_t)jt * 4096 + (size_t)(n * 16 + m) * 64 + jin);
    #pragma unroll
    for (int n = 0; n < 4; ++n)
      acc[n] = __builtin_amdgcn_mfma_f32_16x16x32_f16(af.h, bf[n], acc[n], 0, 0, 0);
  }

  // ---- cross-wave exchange into dedicated red buffer ----
  #pragma unroll
  for (int n = 0; n < 4; ++n)
    #pragma unroll
    for (int r = 0; r < 4; ++r)
      red[(wave * 16 + quad * 4 + r) * 64 + n * 16 + m] = acc[n][r];
  red[4096 + wave * 64 + lane] = rsum;   // raw per-lane rsum (row = lane&15)
  __syncthreads();

  // ---- cooperative reduce + normalize + store: 16 rows x 64 cols ----
  int col = tid & 63;
  int rq  = tid >> 6;
  #pragma unroll
  for (int t = 0; t < 4; ++t) {
    int row = rq * 4 + t;
    float s = 0.f;
    #pragma unroll
    for (int w = 0; w < 4; ++w) s += red[(w * 16 + row) * 64 + col];
    float rs = 0.f;
    #pragma unroll
    for (int w = 0; w < 4; ++w)
      #pragma unroll
      for (int q = 0; q < 4; ++q)
        rs += red[4096 + w * 64 + q * 16 + row];
    out[((size_t)bh * S_LEN + i0 + row) * D_DIM + col] = s / rs;
  }
}

// ---------------- launch ----------------
extern "C" void kernel_launch(void* const* d_in, const int* in_sizes, int n_in,
                              void* d_out, int out_size, void* d_ws, size_t ws_size,
                              hipStream_t stream) {
  const float* Q = (const float*)d_in[0];
  const float* K = (const float*)d_in[1];
  const float* V = (const float*)d_in[2];
  float* out = (float*)d_out;
  char* ws = (char*)d_ws;
  // Layout (total ~88.3 MB < 142,077,952 proven):
  //   code16 [0, 67108864)
  //   hist u32[32768] [67108864, 67239936)
  //   P2 = 67239936:
  //     partial u8 P2+0 .. +3145728            (live hist->hreduce)
  //     qinvD P2+3145728, kinvD P2+3407872     (256 KB each, live norms->qk)
  //     Vt    P2+0 .. +4194304                 (live vt->pv; aliases partial/qinv*, dead by then)
  //     csum  P2+4194304 (256 B, scan1->scan3)
  //     tab2  P2+4195328 (65536 B, scan3->pv)
  //   split arrays (live norms->qk): Qhi 71503872, Qlo 75698176,
  //     Khi 79892480, Klo 84086784 (4 MB each, end 88281088)
  unsigned short* code16  = (unsigned short*)(ws);
  unsigned*       hist    = (unsigned*)(ws + 67108864);
  unsigned char*  partial = (unsigned char*)(ws + 67239936);
  double*         qinvD   = (double*)(ws + 67239936 + 3145728);
  double*         kinvD   = (double*)(ws + 67239936 + 3407872);
  _Float16*       Vt      = (_Float16*)(ws + 67239936);
  unsigned*       csum    = (unsigned*)(ws + 67239936 + 4194304);
  _Float16*       tab2    = (_Float16*)(ws + 67239936 + 4195328);
  unsigned short* Qhi_g   = (unsigned short*)(ws + 71503872);
  unsigned short* Qlo_g   = (unsigned short*)(ws + 75698176);
  unsigned short* Khi_g   = (unsigned short*)(ws + 79892480);
  unsigned short* Klo_g   = (unsigned short*)(ws + 84086784);

  hipMemsetAsync(hist, 0, NB2 * sizeof(unsigned), stream);
  norms_kernel<<<(2 * BH * S_LEN) / 4, 256, 0, stream>>>(
      Q, K, qinvD, kinvD, Qhi_g, Qlo_g, Khi_g, Klo_g);
  qk_mfma_kernel<<<dim3(16, 16, BH), 256, 0, stream>>>(
      Q, K, Qhi_g, Qlo_g, Khi_g, Klo_g, qinvD, kinvD, code16);
  hist_kernel<<<HBLK, 1024, 0, stream>>>((const uint4*)code16, hist, partial);
  hreduce_kernel<<<NHOT_H / 256, 256, 0, stream>>>(partial, hist);
  vt_kernel<<<dim3(16, BH), 256, 0, stream>>>(V, Vt);
  scan1_kernel<<<NCHUNK, 256, 0, stream>>>(hist, csum);
  scan2_kernel<<<1, 256, 0, stream>>>(csum);
  scan3_kernel<<<NCHUNK, 256, 0, stream>>>(hist, csum, tab2);
  pv_mfma_kernel<<<dim3(S_LEN / 16, BH), 256, 0, stream>>>(
      code16, Vt, (const unsigned short*)tab2, out);
}